// Round 3
// baseline (8496.896 us; speedup 1.0000x reference)
//
#include <hip/hip_runtime.h>

typedef __attribute__((ext_vector_type(8))) short short8v;
typedef __attribute__((ext_vector_type(4))) short short4v;
typedef __attribute__((ext_vector_type(4))) float f32x4;
typedef __attribute__((ext_vector_type(4))) float float4v;
typedef unsigned long long u64;

#define NHID 1024
#define NCAT 1024
#define NB   64
#define NT   512
#define NWG  64

__device__ __forceinline__ short f2bf(float f) {
  union { float f; unsigned u; } c; c.f = f;
  unsigned r = (c.u + 0x7fffu + ((c.u >> 16) & 1u)) >> 16;
  return (short)r;
}

union HF { u64 q[2]; short8v v; };

__device__ __forceinline__ u64 ald(const u64* p) {
  return __hip_atomic_load(p, __ATOMIC_RELAXED, __HIP_MEMORY_SCOPE_AGENT);
}

__global__ void cast_kernel(const float* __restrict__ x, const float* __restrict__ h0,
                            short* __restrict__ xb, short* __restrict__ hb0) {
  const long NX4 = (long)NB * NT * NCAT / 4;
  const long NH4 = (long)NB * NHID / 4;
  long i = (long)blockIdx.x * blockDim.x + threadIdx.x;
  long stride = (long)gridDim.x * blockDim.x;
  for (long j = i; j < NX4 + NH4; j += stride) {
    if (j < NH4) {
      float4v v = ((const float4v*)h0)[j];
      short4v s; s[0]=f2bf(v[0]); s[1]=f2bf(v[1]); s[2]=f2bf(v[2]); s[3]=f2bf(v[3]);
      ((short4v*)hb0)[j] = s;
    } else {
      long jj = j - NH4;
      float4v v = ((const float4v*)x)[jj];
      short4v s; s[0]=f2bf(v[0]); s[1]=f2bf(v[1]); s[2]=f2bf(v[2]); s[3]=f2bf(v[3]);
      ((short4v*)xb)[jj] = s;
    }
  }
}

// 64 persistent wgs x 256 threads; wg owns 16 h-cols. Waves split K (h-half/x-half).
// Coherence scheme (fence-free): h published via relaxed agent atomic u16 stores
// (write-through to MALL), wg flag (own 64B line) stored by tid0 AFTER
// __syncthreads (which drains all waves' vmcnt). Consumers poll flags (1 line
// per lane), then read h via relaxed agent atomic u64 loads (always see MALL).
// L2 is never invalidated -> x/weights stay cached; h never lives in L2.
__global__ __launch_bounds__(256, 1) void gru_kernel(
    const float* __restrict__ h0, const float* __restrict__ Wh, const float* __restrict__ Wz,
    const float* __restrict__ Uh, const float* __restrict__ Uz, const float* __restrict__ bz,
    const float* __restrict__ Wout, const short* __restrict__ xb,
    short* __restrict__ hbuf0, short* __restrict__ hbuf1,
    unsigned* __restrict__ flags, float* __restrict__ out)
{
  extern __shared__ char smem[];
  short8v* ufr = (short8v*)smem;               // weight B-frags, 128 KB
  float*   red = (float*)(smem + 131072);      // reduce slots, 24 KB

  const int tid  = threadIdx.x;
  const int wg   = blockIdx.x;
  const int lane = tid & 63;
  const int wm   = tid >> 6;
  const int col  = lane & 15;
  const int quad = lane >> 4;
  const int jg   = wg * 16 + col;
  const int kq   = quad * 8;

  // ---- one-time: weight B-fragments into LDS ----
  for (int idx = tid; idx < 64 * 2 * 64; idx += 256) {
    int l  = idx & 63;
    int nt = (idx >> 6) & 1;
    int kb = idx >> 7;
    int j  = wg * 16 + (l & 15);
    int k0 = kb * 32 + (l >> 4) * 8;
    const float* Us = nt ? Uh : Uz;
    const float* Ws = nt ? Wh : Wz;
    short8v v;
#pragma unroll
    for (int e = 0; e < 8; ++e) {
      int k = k0 + e;
      float f = (k < NHID) ? Us[j * NHID + k] : Ws[j * NCAT + (k - NHID)];
      v[e] = f2bf(f);
    }
    ufr[idx] = v;
  }
  __syncthreads();

  const float bzv = bz[jg];
  float hl[4];
#pragma unroll
  for (int r = 0; r < 4; ++r) hl[r] = h0[(wm * 16 + quad * 4 + r) * NHID + jg];

  short* hb[2] = { hbuf0, hbuf1 };
  const int  kb0  = wm * 16;
  const bool is_h = (wm < 2);
  unsigned* wgflag = flags + wg * 16;           // 64B-strided per-wg flag
  const unsigned* pollp = flags + lane * 16;    // lane i polls wg i

  for (int t = 0; t < NT; ++t) {
    f32x4 pz[4], ph[4];
#pragma unroll
    for (int mt = 0; mt < 4; ++mt) {
      pz[mt] = (f32x4){0.f,0.f,0.f,0.f};
      ph[mt] = (f32x4){0.f,0.f,0.f,0.f};
    }

    if (is_h) {
      if (t > 0) {
        const unsigned tt = (unsigned)t;
        for (;;) {
          unsigned v = __hip_atomic_load(pollp, __ATOMIC_RELAXED, __HIP_MEMORY_SCOPE_AGENT);
          if (__ballot(v < tt) == 0ull) break;
          __builtin_amdgcn_s_sleep(1);
        }
      }
      const short* hc = hb[t & 1];
      const u64* hB[4];
#pragma unroll
      for (int mt = 0; mt < 4; ++mt)
        hB[mt] = (const u64*)(hc + (mt * 16 + col) * NHID + kb0 * 32 + kq);

      HF bufA[16], bufB[16];
      auto loadc = [&](HF* B, int c) {
#pragma unroll
        for (int ii = 0; ii < 4; ++ii) {
#pragma unroll
          for (int mt = 0; mt < 4; ++mt) {
            const u64* p = hB[mt] + (c * 4 + ii) * 8;   // 32 shorts = 8 u64 per kb
            B[ii * 4 + mt].q[0] = ald(p);
            B[ii * 4 + mt].q[1] = ald(p + 1);
          }
        }
      };
      auto cons = [&](HF* B, int c) {
#pragma unroll
        for (int ii = 0; ii < 4; ++ii) {
          int kb = kb0 + c * 4 + ii;
          short8v bzf = ufr[kb * 128 + lane];
          short8v bhf = ufr[kb * 128 + 64 + lane];
#pragma unroll
          for (int mt = 0; mt < 4; ++mt) {
            short8v a = B[ii * 4 + mt].v;
            pz[mt] = __builtin_amdgcn_mfma_f32_16x16x32_bf16(a, bzf, pz[mt], 0, 0, 0);
            ph[mt] = __builtin_amdgcn_mfma_f32_16x16x32_bf16(a, bhf, ph[mt], 0, 0, 0);
          }
        }
      };
      // depth-2 pipeline: 32 fragments in flight
      loadc(bufA, 0); loadc(bufB, 1);
      cons(bufA, 0);  loadc(bufA, 2);
      cons(bufB, 1);  loadc(bufB, 3);
      cons(bufA, 2);  cons(bufB, 3);
    } else {
#pragma unroll 4
      for (int i = 0; i < 16; ++i) {
        int kb = kb0 + i;                       // 32..63
        int xk = (kb - 32) * 32 + kq;
        short8v bzf = ufr[kb * 128 + lane];
        short8v bhf = ufr[kb * 128 + 64 + lane];
#pragma unroll
        for (int mt = 0; mt < 4; ++mt) {
          short8v a = *(const short8v*)(xb + ((long)(mt * 16 + col) * NT + t) * NCAT + xk);
          pz[mt] = __builtin_amdgcn_mfma_f32_16x16x32_bf16(a, bzf, pz[mt], 0, 0, 0);
          ph[mt] = __builtin_amdgcn_mfma_f32_16x16x32_bf16(a, bhf, ph[mt], 0, 0, 0);
        }
      }
    }

    // ---- cross-wave reduce ----
#pragma unroll
    for (int mt = 0; mt < 4; ++mt) {
      if (mt == wm) continue;
      int s = (wm < mt) ? wm : wm - 1;
      float* sl = red + (((mt * 3 + s) * 64) + lane) * 8;
      *(f32x4*)sl       = pz[mt];
      *(f32x4*)(sl + 4) = ph[mt];
    }
    __syncthreads();

    f32x4 accz = pz[wm], acch = ph[wm];
#pragma unroll
    for (int s = 0; s < 3; ++s) {
      const float* sl = red + (((wm * 3 + s) * 64) + lane) * 8;
      accz += *(const f32x4*)sl;
      acch += *(const f32x4*)(sl + 4);
    }

    // ---- epilogue: gates fp32, update register h, publish bf16 (MALL write-through) ----
    short* hn = hb[(t + 1) & 1];
#pragma unroll
    for (int r = 0; r < 4; ++r) {
      float zp = accz[r] + bzv;
      float z  = 1.f / (1.f + __expf(-zp));
      float ht = tanhf(acch[r]);
      float v  = hl[r] + z * (ht - hl[r]);
      hl[r] = v;
      __hip_atomic_store((unsigned short*)&hn[(wm * 16 + quad * 4 + r) * NHID + jg],
                         (unsigned short)f2bf(v), __ATOMIC_RELAXED, __HIP_MEMORY_SCOPE_AGENT);
    }
    asm volatile("s_waitcnt vmcnt(0)" ::: "memory");  // this wave's h stores at MALL
    __syncthreads();                                  // all 4 waves drained
    if (tid == 0)
      __hip_atomic_store(wgflag, (unsigned)(t + 1), __ATOMIC_RELAXED, __HIP_MEMORY_SCOPE_AGENT);
  }

  // ---- tail: out = hT @ Wout.T (hT = hb[0], flag value NT) ----
  {
    for (;;) {
      unsigned v = __hip_atomic_load(pollp, __ATOMIC_RELAXED, __HIP_MEMORY_SCOPE_AGENT);
      if (__ballot(v < (unsigned)NT) == 0ull) break;
      __builtin_amdgcn_s_sleep(1);
    }
    const short* hT = hb[0];
    f32x4 acc = {0.f, 0.f, 0.f, 0.f};
    const u64* hrow2 = (const u64*)(hT + (wm * 16 + col) * NHID + kq);
    const float* wrow = Wout + (long)jg * NHID + kq;
#pragma unroll 4
    for (int kb = 0; kb < 32; ++kb) {
      HF f;
      const u64* p = hrow2 + kb * 8;
      f.q[0] = ald(p); f.q[1] = ald(p + 1);
      float4v w0 = *(const float4v*)(wrow + kb * 32);
      float4v w1 = *(const float4v*)(wrow + kb * 32 + 4);
      short8v b;
      b[0] = f2bf(w0[0]); b[1] = f2bf(w0[1]); b[2] = f2bf(w0[2]); b[3] = f2bf(w0[3]);
      b[4] = f2bf(w1[0]); b[5] = f2bf(w1[1]); b[6] = f2bf(w1[2]); b[7] = f2bf(w1[3]);
      acc = __builtin_amdgcn_mfma_f32_16x16x32_bf16(f.v, b, acc, 0, 0, 0);
    }
#pragma unroll
    for (int r = 0; r < 4; ++r)
      out[(wm * 16 + quad * 4 + r) * NCAT + jg] = acc[r];
  }
}

extern "C" void kernel_launch(void* const* d_in, const int* in_sizes, int n_in,
                              void* d_out, int out_size, void* d_ws, size_t ws_size,
                              hipStream_t stream) {
  const float* x    = (const float*)d_in[0];
  const float* h0   = (const float*)d_in[1];
  const float* Wh   = (const float*)d_in[2];
  const float* Wz   = (const float*)d_in[3];
  const float* Uh   = (const float*)d_in[5];
  const float* Uz   = (const float*)d_in[6];
  const float* bz   = (const float*)d_in[8];
  const float* Wout = (const float*)d_in[10];

  char* ws = (char*)d_ws;
  // layout: flags [0,4K) (64 wgs x 64B) | hb0 128K | hb1 128K | xb bf16 64MB
  unsigned* flags = (unsigned*)ws;
  short* hb0 = (short*)(ws + 4096);
  short* hb1 = (short*)(ws + 4096 + 131072);
  short* xb  = (short*)(ws + 4096 + 262144);

  hipMemsetAsync(flags, 0, 4096, stream);
  cast_kernel<<<4096, 256, 0, stream>>>(x, h0, xb, hb0);

  hipFuncSetAttribute((const void*)gru_kernel,
                      hipFuncAttributeMaxDynamicSharedMemorySize, 155648);
  gru_kernel<<<NWG, 256, 155648, stream>>>(h0, Wh, Wz, Uh, Uz, bz, Wout, xb,
                                           hb0, hb1, flags, (float*)d_out);
}

// Round 4
// 4722.202 us; speedup vs baseline: 1.7994x; 1.7994x over previous
//
#include <hip/hip_runtime.h>

typedef __attribute__((ext_vector_type(8))) short short8v;
typedef __attribute__((ext_vector_type(4))) short short4v;
typedef __attribute__((ext_vector_type(4))) float f32x4;
typedef __attribute__((ext_vector_type(4))) float float4v;

#define NHID 1024
#define NCAT 1024
#define NB   64
#define NT   512

__device__ __forceinline__ short f2bf(float f) {
  union { float f; unsigned u; } c; c.f = f;
  unsigned r = (c.u + 0x7fffu + ((c.u >> 16) & 1u)) >> 16;
  return (short)r;
}

__global__ void cast_kernel(const float* __restrict__ x, const float* __restrict__ h0,
                            short* __restrict__ xb, short* __restrict__ hb0) {
  const long NX4 = (long)NB * NT * NCAT / 4;
  const long NH4 = (long)NB * NHID / 4;
  long i = (long)blockIdx.x * blockDim.x + threadIdx.x;
  long stride = (long)gridDim.x * blockDim.x;
  for (long j = i; j < NX4 + NH4; j += stride) {
    if (j < NH4) {
      float4v v = ((const float4v*)h0)[j];
      short4v s; s[0]=f2bf(v[0]); s[1]=f2bf(v[1]); s[2]=f2bf(v[2]); s[3]=f2bf(v[3]);
      ((short4v*)hb0)[j] = s;
    } else {
      long jj = j - NH4;
      float4v v = ((const float4v*)x)[jj];
      short4v s; s[0]=f2bf(v[0]); s[1]=f2bf(v[1]); s[2]=f2bf(v[2]); s[3]=f2bf(v[3]);
      ((short4v*)xb)[jj] = s;
    }
  }
}

// 256 persistent wgs x 256 threads. wg = (mt = blockIdx>>6, cg = blockIdx&63):
// owns h-tile [rows mt*16..+16) x [cols cg*16..+16). K=2048 fused [h | x_t].
// Waves k-split 512 each: wv0,1 = h-half (poll mt-group flags), wv2,3 = x-half
// (no poll; prefetch next step's x before the barrier). Only wave 0 runs the
// epilogue and publishes the 512B h-tile + the wg flag. One barrier per step.
// 4 independent sync groups of 64 wgs (flags on own 64B lines).
__global__ __launch_bounds__(256, 1) void gru_kernel(
    const float* __restrict__ h0, const float* __restrict__ Wh, const float* __restrict__ Wz,
    const float* __restrict__ Uh, const float* __restrict__ Uz, const float* __restrict__ bz,
    const float* __restrict__ Wout, const short* __restrict__ xb,
    short* __restrict__ hbuf0, short* __restrict__ hbuf1,
    unsigned* __restrict__ flags, float* __restrict__ out)
{
  extern __shared__ char smem[];
  short8v* ufr = (short8v*)smem;               // weight B-frags: [kb*128 + gate*64 + lane], 128 KB
  float*   red = (float*)(smem + 131072);      // reduce slots [par][3][64][8] f32, 12 KB

  const int tid  = threadIdx.x;
  const int lane = tid & 63;
  const int wv   = tid >> 6;
  const int mt   = blockIdx.x >> 6;
  const int cg   = blockIdx.x & 63;
  const int col  = lane & 15;
  const int quad = lane >> 4;
  const int kq   = quad * 8;
  const int jg   = cg * 16 + col;    // owned output column (h-col / cat-col)

  // ---- one-time: weight B-fragments into LDS (16 cols x K=2048 x 2 gates) ----
  for (int idx = tid; idx < 64 * 2 * 64; idx += 256) {
    int l  = idx & 63;
    int nt = (idx >> 6) & 1;          // 0=z gate, 1=h gate
    int kb = idx >> 7;                // 0..63
    int j  = cg * 16 + (l & 15);
    int k0 = (kb & 31) * 32 + (l >> 4) * 8;
    const float* M = (kb < 32) ? (nt ? Uh : Uz) : (nt ? Wh : Wz);
    short8v v;
#pragma unroll
    for (int e = 0; e < 8; ++e) v[e] = f2bf(M[j * 1024 + k0 + e]);
    ufr[idx] = v;
  }
  __syncthreads();

  float hl[4] = {0.f, 0.f, 0.f, 0.f};
  float bzv = 0.f;
  if (wv == 0) {
    bzv = bz[jg];
#pragma unroll
    for (int r = 0; r < 4; ++r) hl[r] = h0[(mt * 16 + quad * 4 + r) * NHID + jg];
  }

  short* hb[2] = { hbuf0, hbuf1 };
  unsigned* myflag = flags + (mt * 64 + cg) * 16;         // own 64B line
  const unsigned* pollp = flags + (mt * 64 + lane) * 16;  // lane l polls wg (mt,l)
  const int kb0 = wv * 16;   // wave k-range: 16 kb (512 K) each

  short8v xf[16];
  if (wv >= 2) {             // preload x for t=0
    const short* xrow = xb + ((long)(mt * 16 + col) * NT + 0) * NCAT + (kb0 - 32) * 32 + kq;
#pragma unroll
    for (int i = 0; i < 16; ++i) xf[i] = *(const short8v*)(xrow + i * 32);
  }

  for (int t = 0; t < NT; ++t) {
    const int par = t & 1;
    f32x4 pz = {0.f,0.f,0.f,0.f}, ph = {0.f,0.f,0.f,0.f};

    if (wv < 2) {
      if (t > 0) {
        const unsigned tt = (unsigned)t;
        for (;;) {
          unsigned v = __hip_atomic_load(pollp, __ATOMIC_RELAXED, __HIP_MEMORY_SCOPE_AGENT);
          if (__ballot(v < tt) == 0ull) break;
          __builtin_amdgcn_s_sleep(1);
        }
        __builtin_amdgcn_fence(__ATOMIC_ACQUIRE, "agent");
      }
      const short* hrow = hb[t & 1] + (mt * 16 + col) * NHID + kb0 * 32 + kq;
      short8v f[16];
#pragma unroll
      for (int i = 0; i < 16; ++i) f[i] = *(const short8v*)(hrow + i * 32);  // all in flight
#pragma unroll
      for (int i = 0; i < 16; ++i) {
        int kb = kb0 + i;
        pz = __builtin_amdgcn_mfma_f32_16x16x32_bf16(f[i], ufr[kb * 128 + lane],      pz, 0, 0, 0);
        ph = __builtin_amdgcn_mfma_f32_16x16x32_bf16(f[i], ufr[kb * 128 + 64 + lane], ph, 0, 0, 0);
      }
    } else {
#pragma unroll
      for (int i = 0; i < 16; ++i) {
        int kb = kb0 + i;
        pz = __builtin_amdgcn_mfma_f32_16x16x32_bf16(xf[i], ufr[kb * 128 + lane],      pz, 0, 0, 0);
        ph = __builtin_amdgcn_mfma_f32_16x16x32_bf16(xf[i], ufr[kb * 128 + 64 + lane], ph, 0, 0, 0);
      }
      if (t + 1 < NT) {  // prefetch next step's x (independent of h -> overlaps poll)
        const short* xrow = xb + ((long)(mt * 16 + col) * NT + (t + 1)) * NCAT + (kb0 - 32) * 32 + kq;
#pragma unroll
        for (int i = 0; i < 16; ++i) xf[i] = *(const short8v*)(xrow + i * 32);
      }
    }

    if (wv != 0) {
      float* sl = red + ((par * 3 + (wv - 1)) * 64 + lane) * 8;
      *(f32x4*)sl       = pz;
      *(f32x4*)(sl + 4) = ph;
    }
    __syncthreads();

    if (wv == 0) {
      f32x4 accz = pz, acch = ph;
#pragma unroll
      for (int s = 0; s < 3; ++s) {
        const float* sl = red + ((par * 3 + s) * 64 + lane) * 8;
        accz += *(const f32x4*)sl;
        acch += *(const f32x4*)(sl + 4);
      }
      short* hn = hb[(t + 1) & 1];
#pragma unroll
      for (int r = 0; r < 4; ++r) {
        float zp = accz[r] + bzv;
        float z  = 1.f / (1.f + __expf(-zp));
        float ht = tanhf(acch[r]);
        float v  = hl[r] + z * (ht - hl[r]);
        hl[r] = v;
        __hip_atomic_store((unsigned short*)&hn[(mt * 16 + quad * 4 + r) * NHID + jg],
                           (unsigned short)f2bf(v), __ATOMIC_RELAXED, __HIP_MEMORY_SCOPE_AGENT);
      }
      asm volatile("s_waitcnt vmcnt(0)" ::: "memory");   // tile stores at coherence point
      if (lane == 0)
        __hip_atomic_store(myflag, (unsigned)(t + 1), __ATOMIC_RELAXED, __HIP_MEMORY_SCOPE_AGENT);
    }
  }

  // ---- tail: out[mt-rows, cg-cats] = hT @ Wout.T, hT = hb[0] ----
  {
    for (;;) {
      unsigned v = __hip_atomic_load(pollp, __ATOMIC_RELAXED, __HIP_MEMORY_SCOPE_AGENT);
      if (__ballot(v < (unsigned)NT) == 0ull) break;
      __builtin_amdgcn_s_sleep(1);
    }
    __builtin_amdgcn_fence(__ATOMIC_ACQUIRE, "agent");

    const int kb0t = wv * 8;   // k-split 256 per wave
    f32x4 acc = {0.f,0.f,0.f,0.f};
    const short* hrow = hb[0] + (mt * 16 + col) * NHID + kb0t * 32 + kq;
    const float* wrow = Wout + (long)jg * NHID + kb0t * 32 + kq;
#pragma unroll 2
    for (int kb = 0; kb < 8; ++kb) {
      short8v a = *(const short8v*)(hrow + kb * 32);
      float4v w0 = *(const float4v*)(wrow + kb * 32);
      float4v w1 = *(const float4v*)(wrow + kb * 32 + 4);
      short8v b;
      b[0] = f2bf(w0[0]); b[1] = f2bf(w0[1]); b[2] = f2bf(w0[2]); b[3] = f2bf(w0[3]);
      b[4] = f2bf(w1[0]); b[5] = f2bf(w1[1]); b[6] = f2bf(w1[2]); b[7] = f2bf(w1[3]);
      acc = __builtin_amdgcn_mfma_f32_16x16x32_bf16(a, b, acc, 0, 0, 0);
    }
    if (wv != 0) {
      float* sl = red + ((wv - 1) * 64 + lane) * 8;
      *(f32x4*)sl = acc;
    }
    __syncthreads();
    if (wv == 0) {
#pragma unroll
      for (int s = 0; s < 3; ++s)
        acc += *(const f32x4*)(red + (s * 64 + lane) * 8);
#pragma unroll
      for (int r = 0; r < 4; ++r)
        out[(mt * 16 + quad * 4 + r) * NCAT + jg] = acc[r];
    }
  }
}

extern "C" void kernel_launch(void* const* d_in, const int* in_sizes, int n_in,
                              void* d_out, int out_size, void* d_ws, size_t ws_size,
                              hipStream_t stream) {
  const float* x    = (const float*)d_in[0];
  const float* h0   = (const float*)d_in[1];
  const float* Wh   = (const float*)d_in[2];
  const float* Wz   = (const float*)d_in[3];
  const float* Uh   = (const float*)d_in[5];
  const float* Uz   = (const float*)d_in[6];
  const float* bz   = (const float*)d_in[8];
  const float* Wout = (const float*)d_in[10];

  char* ws = (char*)d_ws;
  // layout: flags [0,16K) (256 wgs x 64B) | hb0 128K | hb1 128K | xb bf16 64MB
  unsigned* flags = (unsigned*)ws;
  short* hb0 = (short*)(ws + 16384);
  short* hb1 = (short*)(ws + 16384 + 131072);
  short* xb  = (short*)(ws + 16384 + 262144);

  hipMemsetAsync(flags, 0, 16384, stream);
  cast_kernel<<<4096, 256, 0, stream>>>(x, h0, xb, hb0);

  hipFuncSetAttribute((const void*)gru_kernel,
                      hipFuncAttributeMaxDynamicSharedMemorySize, 143360);
  gru_kernel<<<256, 256, 143360, stream>>>(h0, Wh, Wz, Uh, Uz, bz, Wout, xb,
                                           hb0, hb1, flags, (float*)d_out);
}